// Round 9
// baseline (277.026 us; speedup 1.0000x reference)
//
#include <hip/hip_runtime.h>
#include <hip/hip_bf16.h>

typedef __attribute__((ext_vector_type(8))) short short8;
typedef __attribute__((ext_vector_type(4))) float f32x4;
typedef unsigned short u16;

#define TTOK 4096
#define DMOD 512
#define DFFN 2048
#define NEXP 8
#define HEXP 1024

__device__ __forceinline__ u16 to_bf16(float f) {
    union { __hip_bfloat16 h; u16 u; } cv;
    cv.h = __float2bfloat16(f);
    return cv.u;
}

__device__ __forceinline__ float gelu_tanh(float x) {
    const float c = 0.7978845608028654f;
    float y = c * (x + 0.044715f * x * x * x);
    return x / (1.0f + __expf(-2.0f * y));
}

__device__ __forceinline__ float4 ld_bf4(const u16* p) {
    ushort4 u = *(const ushort4*)p;
    union { unsigned i; float f; } a, b, c, d;
    a.i = (unsigned)u.x << 16; b.i = (unsigned)u.y << 16;
    c.i = (unsigned)u.z << 16; d.i = (unsigned)u.w << 16;
    return make_float4(a.f, b.f, c.f, d.f);
}

__device__ __forceinline__ void gload16(const u16* g, u16* l) {
    __builtin_amdgcn_global_load_lds(
        (__attribute__((address_space(1))) void*)g,
        (__attribute__((address_space(3))) void*)l, 16, 0, 0);
}

// ---------------- pack weights fp32 [K,N] -> bf16 fragment-linear ----------------
__global__ __launch_bounds__(256) void pack_weights(
    const float* __restrict__ fc1_w, const float* __restrict__ fc2_w,
    const float* __restrict__ w1, const float* __restrict__ w2,
    u16* __restrict__ fc1p, u16* __restrict__ fc2p,
    u16* __restrict__ w1p, u16* __restrict__ w2p)
{
    int t = blockIdx.x * 256 + threadIdx.x;   // one 16B unit
    const float* src; u16* dst; int N, k, n;
    if (t < 131072) {             // fc1: F=128 S=16 N=2048
        int u = t; int lane = u & 63; int fs = u >> 6; int s = fs & 15;
        int q = lane >> 4, rr = lane & 15;
        src = fc1_w; dst = fc1p + (size_t)u * 8; N = 2048;
        k = s * 32 + q * 8; n = ((fs >> 4) * 16) + rr;
    } else if (t < 262144) {      // fc2: F=32 S=64 N=512
        int u = t - 131072; int lane = u & 63; int fs = u >> 6; int s = fs & 63;
        int q = lane >> 4, rr = lane & 15;
        src = fc2_w; dst = fc2p + (size_t)u * 8; N = 512;
        k = s * 32 + q * 8; n = ((fs >> 6) * 16) + rr;
    } else if (t < 786432) {      // w1: 8 experts, F=64 S=16 N=1024
        int u = t - 262144; int e = u >> 16; int v = u & 65535;
        int lane = v & 63; int fs = v >> 6; int s = fs & 15;
        int q = lane >> 4, rr = lane & 15;
        src = w1 + (size_t)e * 524288; dst = w1p + (size_t)u * 8; N = 1024;
        k = s * 32 + q * 8; n = ((fs >> 4) * 16) + rr;
    } else {                      // w2: 8 experts, F=32 S=32 N=512
        int u = t - 786432; int e = u >> 16; int v = u & 65535;
        int lane = v & 63; int fs = v >> 6; int s = fs & 31;
        int q = lane >> 4, rr = lane & 15;
        src = w2 + (size_t)e * 524288; dst = w2p + (size_t)u * 8; N = 512;
        k = s * 32 + q * 8; n = ((fs >> 5) * 16) + rr;
    }
    u16 ov[8];
#pragma unroll
    for (int j = 0; j < 8; ++j)
        ov[j] = to_bf16(src[(size_t)(k + j) * N + n]);
    *(uint4*)dst = *(uint4*)ov;
}

// ---------------- ln: wave-per-token, lane-major; LN x2 + router logits + feat ----------------
__global__ __launch_bounds__(256) void ln_kernel(
    const float* __restrict__ hidden, const float* __restrict__ raw,
    const float* __restrict__ ln_g, const float* __restrict__ ln_b,
    const float* __restrict__ pre_g, const float* __restrict__ pre_b,
    const float* __restrict__ feat_w, const float* __restrict__ feat_b,
    const float* __restrict__ router_w, const float* __restrict__ router_b,
    u16* __restrict__ xs, float* __restrict__ xbuf, float* __restrict__ featbuf,
    float* __restrict__ logits)
{
    const int tid = threadIdx.x, lane = tid & 63, w = tid >> 6;
    const int t = blockIdx.x * 4 + w;
    __shared__ float pl8[4][64][8];
    __shared__ float raw_sh[4][16];

    const float* xrow = hidden + (size_t)t * DMOD + lane * 8;
    float4 xa = *(const float4*)(xrow);
    float4 xb = *(const float4*)(xrow + 4);
    if (lane < 16) raw_sh[w][lane] = raw[(size_t)t * 16 + lane];

    float s = xa.x + xa.y + xa.z + xa.w + xb.x + xb.y + xb.z + xb.w;
    float q = xa.x*xa.x + xa.y*xa.y + xa.z*xa.z + xa.w*xa.w
            + xb.x*xb.x + xb.y*xb.y + xb.z*xb.z + xb.w*xb.w;
#pragma unroll
    for (int m = 32; m > 0; m >>= 1) { s += __shfl_xor(s, m); q += __shfl_xor(q, m); }
    float mean = s * (1.0f / 512.0f);
    float var  = q * (1.0f / 512.0f) - mean * mean;
    float rstd = rsqrtf(var + 1e-5f);

    float4 na, nb;
    na.x = (xa.x - mean) * rstd; na.y = (xa.y - mean) * rstd;
    na.z = (xa.z - mean) * rstd; na.w = (xa.w - mean) * rstd;
    nb.x = (xb.x - mean) * rstd; nb.y = (xb.y - mean) * rstd;
    nb.z = (xb.z - mean) * rstd; nb.w = (xb.w - mean) * rstd;

    const int d8 = lane * 8;
    float4 pga = *(const float4*)(pre_g + d8), pgb = *(const float4*)(pre_g + d8 + 4);
    float4 pba = *(const float4*)(pre_b + d8), pbb = *(const float4*)(pre_b + d8 + 4);
    u16 ov[8];
    ov[0] = to_bf16(na.x * pga.x + pba.x); ov[1] = to_bf16(na.y * pga.y + pba.y);
    ov[2] = to_bf16(na.z * pga.z + pba.z); ov[3] = to_bf16(na.w * pga.w + pba.w);
    ov[4] = to_bf16(nb.x * pgb.x + pbb.x); ov[5] = to_bf16(nb.y * pgb.y + pbb.y);
    ov[6] = to_bf16(nb.z * pgb.z + pbb.z); ov[7] = to_bf16(nb.w * pgb.w + pbb.w);
    *(uint4*)(xs + (size_t)t * DMOD + d8) = *(uint4*)ov;

    float4 lga = *(const float4*)(ln_g + d8), lgb = *(const float4*)(ln_g + d8 + 4);
    float4 lba = *(const float4*)(ln_b + d8), lbb = *(const float4*)(ln_b + d8 + 4);
    float4 x03, x47;
    x03.x = na.x * lga.x + lba.x; x03.y = na.y * lga.y + lba.y;
    x03.z = na.z * lga.z + lba.z; x03.w = na.w * lga.w + lba.w;
    x47.x = nb.x * lgb.x + lbb.x; x47.y = nb.y * lgb.y + lbb.y;
    x47.z = nb.z * lgb.z + lbb.z; x47.w = nb.w * lgb.w + lbb.w;
    *(float4*)(xbuf + (size_t)t * DMOD + d8) = x03;
    *(float4*)(xbuf + (size_t)t * DMOD + d8 + 4) = x47;

    float4 p03 = make_float4(0.f, 0.f, 0.f, 0.f), p47 = p03;
    const float* rw = router_w + (size_t)d8 * 8;
#pragma unroll
    for (int j = 0; j < 8; ++j) {
        float xv = (j < 4) ? ((j == 0) ? x03.x : (j == 1) ? x03.y : (j == 2) ? x03.z : x03.w)
                           : ((j == 4) ? x47.x : (j == 5) ? x47.y : (j == 6) ? x47.z : x47.w);
        float4 r0 = *(const float4*)(rw + j * 8);
        float4 r1 = *(const float4*)(rw + j * 8 + 4);
        p03.x += xv * r0.x; p03.y += xv * r0.y; p03.z += xv * r0.z; p03.w += xv * r0.w;
        p47.x += xv * r1.x; p47.y += xv * r1.y; p47.z += xv * r1.z; p47.w += xv * r1.w;
    }
    *(float4*)(&pl8[w][lane][0]) = p03;
    *(float4*)(&pl8[w][lane][4]) = p47;
    if (lane < 8) {
        float acc = router_b[lane];
#pragma unroll 8
        for (int i = 0; i < 64; ++i) acc += pl8[w][i][lane];
        logits[(size_t)t * 8 + lane] = acc;
    }

    float fv = feat_b[lane];
#pragma unroll
    for (int f = 0; f < 16; ++f) fv += raw_sh[w][f] * feat_w[f * 64 + lane];
    featbuf[(size_t)t * 64 + lane] = fv;
}

// ---------------- bucket: top-2 + two-level (LDS hist + 8 global atomics/block) ----------------
__global__ __launch_bounds__(256) void bucket_kernel(
    const float* __restrict__ logits, int* __restrict__ cnt, int* __restrict__ slots,
    float* __restrict__ gslot, int* __restrict__ eslot)
{
    const int tid = threadIdx.x;
    const int t = blockIdx.x * 256 + tid;
    __shared__ int csh[8], base[8];
    if (tid < 8) csh[tid] = 0;
    __syncthreads();

    float4 l0 = *(const float4*)(logits + (size_t)t * 8);
    float4 l1 = *(const float4*)(logits + (size_t)t * 8 + 4);
    float v0 = -1e30f, v1 = -1e30f; int i0 = 0, i1 = 0;
#define CK(val, idx) { float v = (val); if (v > v0) { v1 = v0; i1 = i0; v0 = v; i0 = idx; } \
                       else if (v > v1) { v1 = v; i1 = idx; } }
    CK(l0.x, 0) CK(l0.y, 1) CK(l0.z, 2) CK(l0.w, 3)
    CK(l1.x, 4) CK(l1.y, 5) CK(l1.z, 6) CK(l1.w, 7)
#undef CK
    float g1 = 1.0f / (1.0f + __expf(v0 - v1));
    float g0 = 1.0f - g1;
    int r0 = atomicAdd(&csh[i0], 1);
    int r1 = atomicAdd(&csh[i1], 1);
    __syncthreads();
    if (tid < 8) base[tid] = atomicAdd(&cnt[tid], csh[tid]);
    __syncthreads();
    int p0 = base[i0] + r0, p1 = base[i1] + r1;
    slots[i0 * TTOK + p0] = 2 * t;
    slots[i1 * TTOK + p1] = 2 * t + 1;
    gslot[2 * t] = g0;     eslot[2 * t] = i0;
    gslot[2 * t + 1] = g1; eslot[2 * t + 1] = i1;
}

// ---------------- film: 8 tokens/block (bounded live set, no spill) ----------------
__global__ __launch_bounds__(256) void film_kernel(
    const float* __restrict__ xbuf, const float* __restrict__ featbuf,
    const float* __restrict__ film_w, const float* __restrict__ film_b,
    u16* __restrict__ xin)
{
    const int t0 = blockIdx.x * 8, tid = threadIdx.x;
    __shared__ float fs[8 * 64];
#pragma unroll
    for (int i = 0; i < 2; ++i)
        fs[tid + i * 256] = featbuf[(size_t)t0 * 64 + tid + i * 256];
    __syncthreads();

    float acc[8][4];
#pragma unroll
    for (int t = 0; t < 8; ++t) { acc[t][0] = 0.f; acc[t][1] = 0.f; acc[t][2] = 0.f; acc[t][3] = 0.f; }

    for (int j = 0; j < 64; ++j) {
        const float* fw = film_w + (size_t)j * 1024 + tid;
        float w0 = fw[0], w1 = fw[256], w2 = fw[512], w3 = fw[768];
#pragma unroll
        for (int t = 0; t < 8; ++t) {
            float fv = fs[t * 64 + j];
            acc[t][0] += fv * w0; acc[t][1] += fv * w1;
            acc[t][2] += fv * w2; acc[t][3] += fv * w3;
        }
    }
    float b0 = film_b[tid], b1 = film_b[tid + 256], b2 = film_b[tid + 512], b3 = film_b[tid + 768];
#pragma unroll
    for (int t = 0; t < 8; ++t) {
        size_t row = (size_t)(t0 + t) * DMOD;
        float xv0 = xbuf[row + tid], xv1 = xbuf[row + tid + 256];
        xin[row + tid]       = to_bf16(xv0 * (1.0f + acc[t][0] + b0) + acc[t][2] + b2);
        xin[row + tid + 256] = to_bf16(xv1 * (1.0f + acc[t][1] + b1) + acc[t][3] + b3);
    }
}

// ---------------- 64-row A-stationary GEMM core, K sub-chunks of 256, depth-2 B prefetch ----
// LDS: 64 rows x 256 u16 (32KB). Row r: 16B-chunk c stored at phys c^(r&31) (staging DMA:
// lane l of call j fetches logical (l&31)^(r&31), lands at phys l&31 -> reads conflict-~free).
// B packed frag-linear: per-step load = uniform base + lane*16B, depth-2 register dbuf.
// rp[j] = per-lane ptr: row (w*16+2j+(lane>>5)) base + xor-chunk offset (u16 units).
template<int NSTEPS>
__device__ __forceinline__ void gemm64(
    const u16* const rp[8],
    const u16* Bf0, int S, int sbase,
    f32x4 acc[4][4], u16* As)
{
    const int tid = threadIdx.x, lane = tid & 63, w = tid >> 6;
    const int q = lane >> 4, rr = lane & 15;
#pragma unroll
    for (int mi = 0; mi < 4; ++mi)
#pragma unroll
        for (int nj = 0; nj < 4; ++nj) {
            acc[mi][nj][0] = 0.f; acc[mi][nj][1] = 0.f;
            acc[mi][nj][2] = 0.f; acc[mi][nj][3] = 0.f;
        }
    const u16* Bn[4];
#pragma unroll
    for (int i = 0; i < 4; ++i)
        Bn[i] = Bf0 + ((size_t)i * S + sbase) * 512 + lane * 8;

    // stage A sub-chunk 0 (8 DMA calls/wave, 2 rows each)
#pragma unroll
    for (int j = 0; j < 8; ++j)
        gload16(rp[j], As + (w * 16 + 2 * j) * 256);

    short8 bb[2][4];
#pragma unroll
    for (int i = 0; i < 4; ++i) { bb[0][i] = *(const short8*)(Bn[i]); }
#pragma unroll
    for (int i = 0; i < 4; ++i) { bb[1][i] = *(const short8*)(Bn[i] + 512); Bn[i] += 1024; }
    __syncthreads();

    constexpr int NCH = NSTEPS / 8;
    const int ab0 = rr * 256, ab1 = (16 + rr) * 256, ab2 = (32 + rr) * 256, ab3 = (48 + rr) * 256;
#pragma unroll 1
    for (int c = 0; c < NCH; ++c) {
#pragma unroll
        for (int sl = 0; sl < 8; ++sl) {
            short8 b0 = bb[sl & 1][0], b1 = bb[sl & 1][1];
            short8 b2 = bb[sl & 1][2], b3 = bb[sl & 1][3];
            if (c * 8 + sl + 2 < NSTEPS) {
#pragma unroll
                for (int i = 0; i < 4; ++i) bb[sl & 1][i] = *(const short8*)(Bn[i]);
            }
#pragma unroll
            for (int i = 0; i < 4; ++i) Bn[i] += 512;
            int pa = (((sl * 4 + q) ^ rr) & 31) * 8;
            short8 a0 = *(const short8*)(As + ab0 + pa);
            short8 a1 = *(const short8*)(As + ab1 + (pa ^ 128));
            short8 a2 = *(const short8*)(As + ab2 + pa);
            short8 a3 = *(const short8*)(As + ab3 + (pa ^ 128));
            acc[0][0] = __builtin_amdgcn_mfma_f32_16x16x32_bf16(a0, b0, acc[0][0], 0, 0, 0);
            acc[1][0] = __builtin_amdgcn_mfma_f32_16x16x32_bf16(a1, b0, acc[1][0], 0, 0, 0);
            acc[2][0] = __builtin_amdgcn_mfma_f32_16x16x32_bf16(a2, b0, acc[2][0], 0, 0, 0);
            acc[3][0] = __builtin_amdgcn_mfma_f32_16x16x32_bf16(a3, b0, acc[3][0], 0, 0, 0);
            acc[0][1] = __builtin_amdgcn_mfma_f32_16x16x32_bf16(a0, b1, acc[0][1], 0, 0, 0);
            acc[1][1] = __builtin_amdgcn_mfma_f32_16x16x32_bf16(a1, b1, acc[1][1], 0, 0, 0);
            acc[2][1] = __builtin_amdgcn_mfma_f32_16x16x32_bf16(a2, b1, acc[2][1], 0, 0, 0);
            acc[3][1] = __builtin_amdgcn_mfma_f32_16x16x32_bf16(a3, b1, acc[3][1], 0, 0, 0);
            acc[0][2] = __builtin_amdgcn_mfma_f32_16x16x32_bf16(a0, b2, acc[0][2], 0, 0, 0);
            acc[1][2] = __builtin_amdgcn_mfma_f32_16x16x32_bf16(a1, b2, acc[1][2], 0, 0, 0);
            acc[2][2] = __builtin_amdgcn_mfma_f32_16x16x32_bf16(a2, b2, acc[2][2], 0, 0, 0);
            acc[3][2] = __builtin_amdgcn_mfma_f32_16x16x32_bf16(a3, b2, acc[3][2], 0, 0, 0);
            acc[0][3] = __builtin_amdgcn_mfma_f32_16x16x32_bf16(a0, b3, acc[0][3], 0, 0, 0);
            acc[1][3] = __builtin_amdgcn_mfma_f32_16x16x32_bf16(a1, b3, acc[1][3], 0, 0, 0);
            acc[2][3] = __builtin_amdgcn_mfma_f32_16x16x32_bf16(a2, b3, acc[2][3], 0, 0, 0);
            acc[3][3] = __builtin_amdgcn_mfma_f32_16x16x32_bf16(a3, b3, acc[3][3], 0, 0, 0);
        }
        if (c + 1 < NCH) {
            __syncthreads();
#pragma unroll
            for (int j = 0; j < 8; ++j)
                gload16(rp[j] + (c + 1) * 256, As + (w * 16 + 2 * j) * 256);
            __syncthreads();
        }
    }
}

// ---------------- stage1: ffn1 (z==8, y=0..7) + moe1 (z<8, y=0..3) ----------------
__global__ __launch_bounds__(256) void stage1_kernel(
    const u16* __restrict__ xs, const u16* __restrict__ fc1p, const float* __restrict__ fc1_b,
    u16* __restrict__ h1,
    const u16* __restrict__ xin, const u16* __restrict__ w1p, const float* __restrict__ b1,
    const int* __restrict__ cnt, const int* __restrict__ slots, u16* __restrict__ hbuf)
{
    __shared__ __align__(16) u16 As[16384];
    const int tid = threadIdx.x, lane = tid & 63, w = tid >> 6;
    const int cb = lane & 15, rq = (lane >> 4) * 4;
    const int m0 = blockIdx.x * 64;
    const int l31 = lane & 31, lh = lane >> 5;
    const int f0 = blockIdx.y * 16 + w * 4;
    const u16* rp[8];
    f32x4 acc[4][4];

    if (blockIdx.z == 8) {
#pragma unroll
        for (int j = 0; j < 8; ++j) {
            int ri = w * 16 + 2 * j + lh;
            rp[j] = xs + (size_t)(m0 + ri) * 512 + ((l31 ^ (ri & 31)) * 8);
        }
        gemm64<16>(rp, fc1p + (size_t)f0 * 8192, 16, 0, acc, As);
#pragma unroll
        for (int mi = 0; mi < 4; ++mi)
#pragma unroll
            for (int nj = 0; nj < 4; ++nj) {
                int col = (f0 + nj) * 16 + cb;
                float bias = fc1_b[col];
#pragma unroll
                for (int r = 0; r < 4; ++r) {
                    int row = m0 + mi * 16 + rq + r;
                    h1[(size_t)row * DFFN + col] = to_bf16(gelu_tanh(acc[mi][nj][r] + bias));
                }
            }
    } else {
        if (blockIdx.y >= 4) return;
        const int e = blockIdx.z, ce = cnt[e];
        if (m0 >= ce) return;
        const int* sl = slots + e * TTOK;
#pragma unroll
        for (int j = 0; j < 8; ++j) {
            int ri = w * 16 + 2 * j + lh;
            int p = m0 + ri; if (p > ce - 1) p = ce - 1;
            rp[j] = xin + (size_t)(sl[p] >> 1) * 512 + ((l31 ^ (ri & 31)) * 8);
        }
        gemm64<16>(rp, w1p + (size_t)e * 524288 + (size_t)f0 * 8192, 16, 0, acc, As);
#pragma unroll
        for (int mi = 0; mi < 4; ++mi)
#pragma unroll
            for (int r = 0; r < 4; ++r) {
                int p = m0 + mi * 16 + rq + r;
                if (p < ce) {
                    int slot = sl[p];
#pragma unroll
                    for (int nj = 0; nj < 4; ++nj) {
                        int col = (f0 + nj) * 16 + cb;
                        hbuf[(size_t)slot * HEXP + col] = to_bf16(gelu_tanh(acc[mi][nj][r] + b1[e * HEXP + col]));
                    }
                }
            }
    }
}

// ---------------- stage2: ffn2 (z==8) + moe2 (z<8); y = nb*2 + ks ----------------
__global__ __launch_bounds__(256) void stage2_kernel(
    const u16* __restrict__ h1, const u16* __restrict__ fc2p,
    const u16* __restrict__ hbuf, const u16* __restrict__ w2p,
    const int* __restrict__ cnt, const int* __restrict__ slots,
    u16* __restrict__ pf, u16* __restrict__ pm)
{
    __shared__ __align__(16) u16 As[16384];
    const int tid = threadIdx.x, lane = tid & 63, w = tid >> 6;
    const int cb = lane & 15, rq = (lane >> 4) * 4;
    const int m0 = blockIdx.x * 64;
    const int l31 = lane & 31, lh = lane >> 5;
    const int ks = blockIdx.y & 1, nb = blockIdx.y >> 1;
    const int f0 = nb * 16 + w * 4;
    const u16* rp[8];
    f32x4 acc[4][4];

    if (blockIdx.z == 8) {
#pragma unroll
        for (int j = 0; j < 8; ++j) {
            int ri = w * 16 + 2 * j + lh;
            rp[j] = h1 + (size_t)(m0 + ri) * DFFN + ks * 1024 + ((l31 ^ (ri & 31)) * 8);
        }
        gemm64<32>(rp, fc2p + (size_t)f0 * 32768, 64, ks * 32, acc, As);
        u16* dst = pf + (size_t)ks * TTOK * DMOD;
#pragma unroll
        for (int mi = 0; mi < 4; ++mi)
#pragma unroll
            for (int nj = 0; nj < 4; ++nj) {
                int col = (f0 + nj) * 16 + cb;
#pragma unroll
                for (int r = 0; r < 4; ++r) {
                    int row = m0 + mi * 16 + rq + r;
                    dst[(size_t)row * DMOD + col] = to_bf16(acc[mi][nj][r]);
                }
            }
    } else {
        const int e = blockIdx.z, ce = cnt[e];
        if (m0 >= ce) return;
        const int* sl = slots + e * TTOK;
#pragma unroll
        for (int j = 0; j < 8; ++j) {
            int ri = w * 16 + 2 * j + lh;
            int p = m0 + ri; if (p > ce - 1) p = ce - 1;
            rp[j] = hbuf + (size_t)sl[p] * HEXP + ks * 512 + ((l31 ^ (ri & 31)) * 8);
        }
        gemm64<16>(rp, w2p + (size_t)e * 524288 + (size_t)f0 * 16384, 32, ks * 16, acc, As);
        u16* dst = pm + (size_t)ks * 2 * TTOK * DMOD;
#pragma unroll
        for (int mi = 0; mi < 4; ++mi)
#pragma unroll
            for (int r = 0; r < 4; ++r) {
                int p = m0 + mi * 16 + rq + r;
                if (p < ce) {
                    int slot = sl[p];
#pragma unroll
                    for (int nj = 0; nj < 4; ++nj) {
                        int col = (f0 + nj) * 16 + cb;
                        dst[(size_t)slot * DMOD + col] = to_bf16(acc[mi][nj][r]);
                    }
                }
            }
    }
}

// ---------------- combine: out = hidden + ffn2(+bias) + alpha*(gated moe(+bias)) ----------------
__global__ __launch_bounds__(256) void combine_kernel(
    const float* __restrict__ hidden, const u16* __restrict__ pf, const u16* __restrict__ pm,
    const float* __restrict__ fc2_b, const float* __restrict__ b2,
    const float* __restrict__ gslot, const int* __restrict__ eslot,
    const float* __restrict__ alpha, float* __restrict__ out)
{
    int i = blockIdx.x * 256 + threadIdx.x;     // float4 index over T*D/4
    int t = i >> 7, d = (i & 127) * 4;
    float a = alpha[0];
    float4 h = ((const float4*)hidden)[i];
    float4 bias = *(const float4*)(fc2_b + d);

    size_t fo = (size_t)t * DMOD + d;
    float4 f0 = ld_bf4(pf + fo), f1 = ld_bf4(pf + (size_t)TTOK * DMOD + fo);

    int s0 = 2 * t, s1 = 2 * t + 1;
    float g0 = gslot[s0], g1 = gslot[s1];
    int e0 = eslot[s0], e1 = eslot[s1];
    size_t mo0 = (size_t)s0 * DMOD + d, mo1 = (size_t)s1 * DMOD + d;
    const u16* pm1 = pm + (size_t)2 * TTOK * DMOD;
    float4 ma = ld_bf4(pm + mo0), mb = ld_bf4(pm1 + mo0);
    float4 mc = ld_bf4(pm + mo1), md = ld_bf4(pm1 + mo1);
    float4 ba = *(const float4*)(b2 + e0 * DMOD + d);
    float4 bb = *(const float4*)(b2 + e1 * DMOD + d);

    float4 o;
    o.x = h.x + f0.x + f1.x + bias.x + a * (g0 * (ma.x + mb.x + ba.x) + g1 * (mc.x + md.x + bb.x));
    o.y = h.y + f0.y + f1.y + bias.y + a * (g0 * (ma.y + mb.y + ba.y) + g1 * (mc.y + md.y + bb.y));
    o.z = h.z + f0.z + f1.z + bias.z + a * (g0 * (ma.z + mb.z + ba.z) + g1 * (mc.z + md.z + bb.z));
    o.w = h.w + f0.w + f1.w + bias.w + a * (g0 * (ma.w + mb.w + ba.w) + g1 * (mc.w + md.w + bb.w));
    ((float4*)out)[i] = o;
}

extern "C" void kernel_launch(void* const* d_in, const int* in_sizes, int n_in,
                              void* d_out, int out_size, void* d_ws, size_t ws_size,
                              hipStream_t stream)
{
    const float* hidden   = (const float*)d_in[0];
    const float* raw      = (const float*)d_in[1];
    const float* ln_g     = (const float*)d_in[2];
    const float* ln_b     = (const float*)d_in[3];
    const float* pre_g    = (const float*)d_in[4];
    const float* pre_b    = (const float*)d_in[5];
    const float* feat_w   = (const float*)d_in[6];
    const float* feat_b   = (const float*)d_in[7];
    const float* film_w   = (const float*)d_in[8];
    const float* film_b   = (const float*)d_in[9];
    const float* router_w = (const float*)d_in[10];
    const float* router_b = (const float*)d_in[11];
    const float* w1       = (const float*)d_in[12];
    const float* b1       = (const float*)d_in[13];
    const float* w2       = (const float*)d_in[14];
    const float* b2       = (const float*)d_in[15];
    const float* fc1_w    = (const float*)d_in[16];
    const float* fc1_b    = (const float*)d_in[17];
    const float* fc2_w    = (const float*)d_in[18];
    const float* fc2_b    = (const float*)d_in[19];
    const float* alpha    = (const float*)d_in[20];
    float* out = (float*)d_out;

    char* w = (char*)d_ws;
    auto alloc = [&](size_t b) { char* p = w; w += (b + 255) & ~(size_t)255; return p; };
    u16*  fc1p = (u16*)alloc((size_t)DFFN * DMOD * 2);
    u16*  fc2p = (u16*)alloc((size_t)DMOD * DFFN * 2);
    u16*  w1p  = (u16*)alloc((size_t)NEXP * HEXP * DMOD * 2);
    u16*  w2p  = (u16*)alloc((size_t)NEXP * DMOD * HEXP * 2);
    u16*  xs   = (u16*)alloc((size_t)TTOK * DMOD * 2);
    u16*  xin  = (u16*)alloc((size_t)TTOK * DMOD * 2);
    u16*  h1   = (u16*)alloc((size_t)TTOK * DFFN * 2);
    u16*  hb   = (u16*)alloc((size_t)2 * TTOK * HEXP * 2);
    u16*  pf   = (u16*)alloc((size_t)2 * TTOK * DMOD * 2);
    u16*  pm   = (u16*)alloc((size_t)2 * 2 * TTOK * DMOD * 2);
    int*   cnt   = (int*)alloc(NEXP * 4);
    int*   slots = (int*)alloc((size_t)NEXP * TTOK * 4);
    float* gslot = (float*)alloc((size_t)2 * TTOK * 4);
    int*   eslot = (int*)alloc((size_t)2 * TTOK * 4);
    float* logits = (float*)alloc((size_t)TTOK * 8 * 4);
    float* xbuf  = (float*)pm;      // fp32 [T,D]=8MB, consumed by film before stage2 writes pm
    float* featbuf = (float*)h1;    // 1MB, consumed by film before stage1 writes h1

    hipMemsetAsync(cnt, 0, NEXP * 4, stream);
    pack_weights<<<5120, 256, 0, stream>>>(fc1_w, fc2_w, w1, w2, fc1p, fc2p, w1p, w2p);
    ln_kernel<<<1024, 256, 0, stream>>>(hidden, raw, ln_g, ln_b, pre_g, pre_b,
        feat_w, feat_b, router_w, router_b, xs, xbuf, featbuf, logits);
    bucket_kernel<<<16, 256, 0, stream>>>(logits, cnt, slots, gslot, eslot);
    film_kernel<<<512, 256, 0, stream>>>(xbuf, featbuf, film_w, film_b, xin);
    stage1_kernel<<<dim3(64, 8, 9), 256, 0, stream>>>(xs, fc1p, fc1_b, h1,
        xin, w1p, b1, cnt, slots, hb);
    stage2_kernel<<<dim3(64, 4, 9), 256, 0, stream>>>(h1, fc2p, hb, w2p, cnt, slots, pf, pm);
    combine_kernel<<<2048, 256, 0, stream>>>(hidden, pf, pm, fc2_b, b2, gslot, eslot, alpha, out);
}

// Round 10
// 259.187 us; speedup vs baseline: 1.0688x; 1.0688x over previous
//
#include <hip/hip_runtime.h>
#include <hip/hip_bf16.h>

typedef __attribute__((ext_vector_type(8))) short short8;
typedef __attribute__((ext_vector_type(4))) float f32x4;
typedef unsigned short u16;

#define TTOK 4096
#define DMOD 512
#define DFFN 2048
#define NEXP 8
#define HEXP 1024

__device__ __forceinline__ u16 to_bf16(float f) {
    union { __hip_bfloat16 h; u16 u; } cv;
    cv.h = __float2bfloat16(f);
    return cv.u;
}

__device__ __forceinline__ float gelu_tanh(float x) {
    const float c = 0.7978845608028654f;
    float y = c * (x + 0.044715f * x * x * x);
    return x / (1.0f + __expf(-2.0f * y));
}

__device__ __forceinline__ float4 ld_bf4(const u16* p) {
    ushort4 u = *(const ushort4*)p;
    union { unsigned i; float f; } a, b, c, d;
    a.i = (unsigned)u.x << 16; b.i = (unsigned)u.y << 16;
    c.i = (unsigned)u.z << 16; d.i = (unsigned)u.w << 16;
    return make_float4(a.f, b.f, c.f, d.f);
}

__device__ __forceinline__ void gload16(const u16* g, u16* l) {
    __builtin_amdgcn_global_load_lds(
        (__attribute__((address_space(1))) void*)g,
        (__attribute__((address_space(3))) void*)l, 16, 0, 0);
}

// ---------------- pack weights fp32 [K,N] -> bf16 fragment-linear ----------------
__global__ __launch_bounds__(256) void pack_weights(
    const float* __restrict__ fc1_w, const float* __restrict__ fc2_w,
    const float* __restrict__ w1, const float* __restrict__ w2,
    u16* __restrict__ fc1p, u16* __restrict__ fc2p,
    u16* __restrict__ w1p, u16* __restrict__ w2p)
{
    int t = blockIdx.x * 256 + threadIdx.x;   // one 16B unit
    const float* src; u16* dst; int N, k, n;
    if (t < 131072) {             // fc1: F=128 S=16 N=2048
        int u = t; int lane = u & 63; int fs = u >> 6; int s = fs & 15;
        int q = lane >> 4, rr = lane & 15;
        src = fc1_w; dst = fc1p + (size_t)u * 8; N = 2048;
        k = s * 32 + q * 8; n = ((fs >> 4) * 16) + rr;
    } else if (t < 262144) {      // fc2: F=32 S=64 N=512
        int u = t - 131072; int lane = u & 63; int fs = u >> 6; int s = fs & 63;
        int q = lane >> 4, rr = lane & 15;
        src = fc2_w; dst = fc2p + (size_t)u * 8; N = 512;
        k = s * 32 + q * 8; n = ((fs >> 6) * 16) + rr;
    } else if (t < 786432) {      // w1: 8 experts, F=64 S=16 N=1024
        int u = t - 262144; int e = u >> 16; int v = u & 65535;
        int lane = v & 63; int fs = v >> 6; int s = fs & 15;
        int q = lane >> 4, rr = lane & 15;
        src = w1 + (size_t)e * 524288; dst = w1p + (size_t)u * 8; N = 1024;
        k = s * 32 + q * 8; n = ((fs >> 4) * 16) + rr;
    } else {                      // w2: 8 experts, F=32 S=32 N=512
        int u = t - 786432; int e = u >> 16; int v = u & 65535;
        int lane = v & 63; int fs = v >> 6; int s = fs & 31;
        int q = lane >> 4, rr = lane & 15;
        src = w2 + (size_t)e * 524288; dst = w2p + (size_t)u * 8; N = 512;
        k = s * 32 + q * 8; n = ((fs >> 5) * 16) + rr;
    }
    u16 ov[8];
#pragma unroll
    for (int j = 0; j < 8; ++j)
        ov[j] = to_bf16(src[(size_t)(k + j) * N + n]);
    *(uint4*)dst = *(uint4*)ov;
}

// ---------------- ln: wave-per-token, lane-major; LN x2 + router logits + feat ----------------
__global__ __launch_bounds__(256) void ln_kernel(
    const float* __restrict__ hidden, const float* __restrict__ raw,
    const float* __restrict__ ln_g, const float* __restrict__ ln_b,
    const float* __restrict__ pre_g, const float* __restrict__ pre_b,
    const float* __restrict__ feat_w, const float* __restrict__ feat_b,
    const float* __restrict__ router_w, const float* __restrict__ router_b,
    u16* __restrict__ xs, float* __restrict__ xbuf, float* __restrict__ featbuf,
    float* __restrict__ logits)
{
    const int tid = threadIdx.x, lane = tid & 63, w = tid >> 6;
    const int t = blockIdx.x * 4 + w;
    __shared__ float pl8[4][64][8];
    __shared__ float raw_sh[4][16];

    const float* xrow = hidden + (size_t)t * DMOD + lane * 8;
    float4 xa = *(const float4*)(xrow);
    float4 xb = *(const float4*)(xrow + 4);
    if (lane < 16) raw_sh[w][lane] = raw[(size_t)t * 16 + lane];

    float s = xa.x + xa.y + xa.z + xa.w + xb.x + xb.y + xb.z + xb.w;
    float q = xa.x*xa.x + xa.y*xa.y + xa.z*xa.z + xa.w*xa.w
            + xb.x*xb.x + xb.y*xb.y + xb.z*xb.z + xb.w*xb.w;
#pragma unroll
    for (int m = 32; m > 0; m >>= 1) { s += __shfl_xor(s, m); q += __shfl_xor(q, m); }
    float mean = s * (1.0f / 512.0f);
    float var  = q * (1.0f / 512.0f) - mean * mean;
    float rstd = rsqrtf(var + 1e-5f);

    float4 na, nb;
    na.x = (xa.x - mean) * rstd; na.y = (xa.y - mean) * rstd;
    na.z = (xa.z - mean) * rstd; na.w = (xa.w - mean) * rstd;
    nb.x = (xb.x - mean) * rstd; nb.y = (xb.y - mean) * rstd;
    nb.z = (xb.z - mean) * rstd; nb.w = (xb.w - mean) * rstd;

    const int d8 = lane * 8;
    float4 pga = *(const float4*)(pre_g + d8), pgb = *(const float4*)(pre_g + d8 + 4);
    float4 pba = *(const float4*)(pre_b + d8), pbb = *(const float4*)(pre_b + d8 + 4);
    u16 ov[8];
    ov[0] = to_bf16(na.x * pga.x + pba.x); ov[1] = to_bf16(na.y * pga.y + pba.y);
    ov[2] = to_bf16(na.z * pga.z + pba.z); ov[3] = to_bf16(na.w * pga.w + pba.w);
    ov[4] = to_bf16(nb.x * pgb.x + pbb.x); ov[5] = to_bf16(nb.y * pgb.y + pbb.y);
    ov[6] = to_bf16(nb.z * pgb.z + pbb.z); ov[7] = to_bf16(nb.w * pgb.w + pbb.w);
    *(uint4*)(xs + (size_t)t * DMOD + d8) = *(uint4*)ov;

    float4 lga = *(const float4*)(ln_g + d8), lgb = *(const float4*)(ln_g + d8 + 4);
    float4 lba = *(const float4*)(ln_b + d8), lbb = *(const float4*)(ln_b + d8 + 4);
    float4 x03, x47;
    x03.x = na.x * lga.x + lba.x; x03.y = na.y * lga.y + lba.y;
    x03.z = na.z * lga.z + lba.z; x03.w = na.w * lga.w + lba.w;
    x47.x = nb.x * lgb.x + lbb.x; x47.y = nb.y * lgb.y + lbb.y;
    x47.z = nb.z * lgb.z + lbb.z; x47.w = nb.w * lgb.w + lbb.w;
    *(float4*)(xbuf + (size_t)t * DMOD + d8) = x03;
    *(float4*)(xbuf + (size_t)t * DMOD + d8 + 4) = x47;

    float4 p03 = make_float4(0.f, 0.f, 0.f, 0.f), p47 = p03;
    const float* rw = router_w + (size_t)d8 * 8;
#pragma unroll
    for (int j = 0; j < 8; ++j) {
        float xv = (j < 4) ? ((j == 0) ? x03.x : (j == 1) ? x03.y : (j == 2) ? x03.z : x03.w)
                           : ((j == 4) ? x47.x : (j == 5) ? x47.y : (j == 6) ? x47.z : x47.w);
        float4 r0 = *(const float4*)(rw + j * 8);
        float4 r1 = *(const float4*)(rw + j * 8 + 4);
        p03.x += xv * r0.x; p03.y += xv * r0.y; p03.z += xv * r0.z; p03.w += xv * r0.w;
        p47.x += xv * r1.x; p47.y += xv * r1.y; p47.z += xv * r1.z; p47.w += xv * r1.w;
    }
    *(float4*)(&pl8[w][lane][0]) = p03;
    *(float4*)(&pl8[w][lane][4]) = p47;
    if (lane < 8) {
        float acc = router_b[lane];
#pragma unroll 8
        for (int i = 0; i < 64; ++i) acc += pl8[w][i][lane];
        logits[(size_t)t * 8 + lane] = acc;
    }

    float fv = feat_b[lane];
#pragma unroll
    for (int f = 0; f < 16; ++f) fv += raw_sh[w][f] * feat_w[f * 64 + lane];
    featbuf[(size_t)t * 64 + lane] = fv;
}

// ---------------- bucket: top-2 + two-level (LDS hist + 8 global atomics/block) ----------------
__global__ __launch_bounds__(256) void bucket_kernel(
    const float* __restrict__ logits, int* __restrict__ cnt, int* __restrict__ slots,
    float* __restrict__ gslot, int* __restrict__ eslot)
{
    const int tid = threadIdx.x;
    const int t = blockIdx.x * 256 + tid;
    __shared__ int csh[8], base[8];
    if (tid < 8) csh[tid] = 0;
    __syncthreads();

    float4 l0 = *(const float4*)(logits + (size_t)t * 8);
    float4 l1 = *(const float4*)(logits + (size_t)t * 8 + 4);
    float v0 = -1e30f, v1 = -1e30f; int i0 = 0, i1 = 0;
#define CK(val, idx) { float v = (val); if (v > v0) { v1 = v0; i1 = i0; v0 = v; i0 = idx; } \
                       else if (v > v1) { v1 = v; i1 = idx; } }
    CK(l0.x, 0) CK(l0.y, 1) CK(l0.z, 2) CK(l0.w, 3)
    CK(l1.x, 4) CK(l1.y, 5) CK(l1.z, 6) CK(l1.w, 7)
#undef CK
    float g1 = 1.0f / (1.0f + __expf(v0 - v1));
    float g0 = 1.0f - g1;
    int r0 = atomicAdd(&csh[i0], 1);
    int r1 = atomicAdd(&csh[i1], 1);
    __syncthreads();
    if (tid < 8) base[tid] = atomicAdd(&cnt[tid], csh[tid]);
    __syncthreads();
    int p0 = base[i0] + r0, p1 = base[i1] + r1;
    slots[i0 * TTOK + p0] = 2 * t;
    slots[i1 * TTOK + p1] = 2 * t + 1;
    gslot[2 * t] = g0;     eslot[2 * t] = i0;
    gslot[2 * t + 1] = g1; eslot[2 * t + 1] = i1;
}

// ---------------- film: 8 tokens/block (bounded live set, no spill) ----------------
__global__ __launch_bounds__(256) void film_kernel(
    const float* __restrict__ xbuf, const float* __restrict__ featbuf,
    const float* __restrict__ film_w, const float* __restrict__ film_b,
    u16* __restrict__ xin)
{
    const int t0 = blockIdx.x * 8, tid = threadIdx.x;
    __shared__ float fs[8 * 64];
#pragma unroll
    for (int i = 0; i < 2; ++i)
        fs[tid + i * 256] = featbuf[(size_t)t0 * 64 + tid + i * 256];
    __syncthreads();

    float acc[8][4];
#pragma unroll
    for (int t = 0; t < 8; ++t) { acc[t][0] = 0.f; acc[t][1] = 0.f; acc[t][2] = 0.f; acc[t][3] = 0.f; }

    for (int j = 0; j < 64; ++j) {
        const float* fw = film_w + (size_t)j * 1024 + tid;
        float w0 = fw[0], w1 = fw[256], w2 = fw[512], w3 = fw[768];
#pragma unroll
        for (int t = 0; t < 8; ++t) {
            float fv = fs[t * 64 + j];
            acc[t][0] += fv * w0; acc[t][1] += fv * w1;
            acc[t][2] += fv * w2; acc[t][3] += fv * w3;
        }
    }
    float b0 = film_b[tid], b1 = film_b[tid + 256], b2 = film_b[tid + 512], b3 = film_b[tid + 768];
#pragma unroll
    for (int t = 0; t < 8; ++t) {
        size_t row = (size_t)(t0 + t) * DMOD;
        float xv0 = xbuf[row + tid], xv1 = xbuf[row + tid + 256];
        xin[row + tid]       = to_bf16(xv0 * (1.0f + acc[t][0] + b0) + acc[t][2] + b2);
        xin[row + tid + 256] = to_bf16(xv1 * (1.0f + acc[t][1] + b1) + acc[t][3] + b3);
    }
}

// ---------------- 32-row A-stationary GEMM core (r8 shape) + DEPTH-2 B prefetch ----------------
// r8 measured: MfmaUtil 14.6% with depth-1 B prefetch (136cyc lead < 200-300cyc L2 latency).
// Depth-2 ping-pong bb[2][4]: load issued 2 steps (~272cyc) ahead. VGPR +16 (64->~96),
// still 5 waves/SIMD; LDS 32KB -> 5 blocks/CU. r9's 64-row variant regressed (VGPR 128,
// occupancy 12%) -- do NOT grow the tile.
template<int KCHUNKS>
__device__ __forceinline__ void gemm32(
    const u16* const rp[8],
    const u16* Bf0, int S, int sbase,
    f32x4 acc[2][4], u16* As)
{
    const int tid = threadIdx.x, lane = tid & 63, w = tid >> 6;
    const int q = lane >> 4, rr = lane & 15, l7 = lane & 7;
#pragma unroll
    for (int mi = 0; mi < 2; ++mi)
#pragma unroll
        for (int nj = 0; nj < 4; ++nj) {
            acc[mi][nj][0] = 0.f; acc[mi][nj][1] = 0.f;
            acc[mi][nj][2] = 0.f; acc[mi][nj][3] = 0.f;
        }
    const u16* Bi[4];
#pragma unroll
    for (int i = 0; i < 4; ++i)
        Bi[i] = Bf0 + ((size_t)i * S + sbase) * 512 + lane * 8;

#pragma unroll
    for (int i = 0; i < 8; ++i)
        gload16(rp[i] + (lane ^ i) * 8, As + (w * 8 + i) * 512);

    short8 bb[2][4];
#pragma unroll
    for (int i = 0; i < 4; ++i) bb[0][i] = *(const short8*)(Bi[i]);
#pragma unroll
    for (int i = 0; i < 4; ++i) bb[1][i] = *(const short8*)(Bi[i] + 512);
    __syncthreads();

    const int a0base = rr * 512, a1base = (16 + rr) * 512;
#pragma unroll
    for (int c = 0; c < KCHUNKS; ++c) {
#pragma unroll
        for (int sl = 0; sl < 16; ++sl) {
            short8 b0 = bb[sl & 1][0], b1 = bb[sl & 1][1];
            short8 b2 = bb[sl & 1][2], b3 = bb[sl & 1][3];
            int t2 = c * 16 + sl + 2;
            if (t2 < KCHUNKS * 16) {
#pragma unroll
                for (int i = 0; i < 4; ++i)
                    bb[sl & 1][i] = *(const short8*)(Bi[i] + (size_t)t2 * 512);
            }
            int pa = ((sl * 4 + q) ^ l7) * 8;
            short8 a0 = *(const short8*)(As + a0base + pa);
            short8 a1 = *(const short8*)(As + a1base + pa);
            acc[0][0] = __builtin_amdgcn_mfma_f32_16x16x32_bf16(a0, b0, acc[0][0], 0, 0, 0);
            acc[1][0] = __builtin_amdgcn_mfma_f32_16x16x32_bf16(a1, b0, acc[1][0], 0, 0, 0);
            acc[0][1] = __builtin_amdgcn_mfma_f32_16x16x32_bf16(a0, b1, acc[0][1], 0, 0, 0);
            acc[1][1] = __builtin_amdgcn_mfma_f32_16x16x32_bf16(a1, b1, acc[1][1], 0, 0, 0);
            acc[0][2] = __builtin_amdgcn_mfma_f32_16x16x32_bf16(a0, b2, acc[0][2], 0, 0, 0);
            acc[1][2] = __builtin_amdgcn_mfma_f32_16x16x32_bf16(a1, b2, acc[1][2], 0, 0, 0);
            acc[0][3] = __builtin_amdgcn_mfma_f32_16x16x32_bf16(a0, b3, acc[0][3], 0, 0, 0);
            acc[1][3] = __builtin_amdgcn_mfma_f32_16x16x32_bf16(a1, b3, acc[1][3], 0, 0, 0);
        }
        if (c + 1 < KCHUNKS) {
            __syncthreads();
#pragma unroll
            for (int i = 0; i < 8; ++i)
                gload16(rp[i] + (c + 1) * 512 + (lane ^ i) * 8, As + (w * 8 + i) * 512);
            __syncthreads();
        }
    }
}

// ---------------- stage1: ffn1 (z==8, y=0..7) + moe1 (z<8, y=0..3) ----------------
__global__ __launch_bounds__(256) void stage1_kernel(
    const u16* __restrict__ xs, const u16* __restrict__ fc1p, const float* __restrict__ fc1_b,
    u16* __restrict__ h1,
    const u16* __restrict__ xin, const u16* __restrict__ w1p, const float* __restrict__ b1,
    const int* __restrict__ cnt, const int* __restrict__ slots, u16* __restrict__ hbuf)
{
    __shared__ __align__(16) u16 As[16384];
    const int tid = threadIdx.x, lane = tid & 63, w = tid >> 6;
    const int cb = lane & 15, rq = (lane >> 4) * 4;
    const int m0 = blockIdx.x * 32;
    const u16* rp[8];
    f32x4 acc[2][4];

    if (blockIdx.z == 8) {
        const int f0 = blockIdx.y * 16 + w * 4;
#pragma unroll
        for (int i = 0; i < 8; ++i) rp[i] = xs + (size_t)(m0 + w * 8 + i) * 512;
        gemm32<1>(rp, fc1p + (size_t)f0 * 8192, 16, 0, acc, As);
#pragma unroll
        for (int mi = 0; mi < 2; ++mi)
#pragma unroll
            for (int nj = 0; nj < 4; ++nj) {
                int col = (f0 + nj) * 16 + cb;
                float bias = fc1_b[col];
#pragma unroll
                for (int r = 0; r < 4; ++r) {
                    int row = m0 + mi * 16 + rq + r;
                    h1[(size_t)row * DFFN + col] = to_bf16(gelu_tanh(acc[mi][nj][r] + bias));
                }
            }
    } else {
        if (blockIdx.y >= 4) return;
        const int e = blockIdx.z, ce = cnt[e];
        if (m0 >= ce) return;
        const int* sl = slots + e * TTOK;
        const int f0 = blockIdx.y * 16 + w * 4;
#pragma unroll
        for (int i = 0; i < 8; ++i) {
            int p = m0 + w * 8 + i; if (p > ce - 1) p = ce - 1;
            rp[i] = xin + (size_t)(sl[p] >> 1) * 512;
        }
        gemm32<1>(rp, w1p + (size_t)e * 524288 + (size_t)f0 * 8192, 16, 0, acc, As);
#pragma unroll
        for (int mi = 0; mi < 2; ++mi)
#pragma unroll
            for (int r = 0; r < 4; ++r) {
                int p = m0 + mi * 16 + rq + r;
                if (p < ce) {
                    int slot = sl[p];
#pragma unroll
                    for (int nj = 0; nj < 4; ++nj) {
                        int col = (f0 + nj) * 16 + cb;
                        hbuf[(size_t)slot * HEXP + col] = to_bf16(gelu_tanh(acc[mi][nj][r] + b1[e * HEXP + col]));
                    }
                }
            }
    }
}

// ---------------- stage2: ffn2 (z==8) + moe2 (z<8); y = nb*2 + ks ----------------
__global__ __launch_bounds__(256) void stage2_kernel(
    const u16* __restrict__ h1, const u16* __restrict__ fc2p,
    const u16* __restrict__ hbuf, const u16* __restrict__ w2p,
    const int* __restrict__ cnt, const int* __restrict__ slots,
    u16* __restrict__ pf, u16* __restrict__ pm)
{
    __shared__ __align__(16) u16 As[16384];
    const int tid = threadIdx.x, lane = tid & 63, w = tid >> 6;
    const int cb = lane & 15, rq = (lane >> 4) * 4;
    const int m0 = blockIdx.x * 32;
    const int ks = blockIdx.y & 1, nb = blockIdx.y >> 1;
    const int f0 = nb * 16 + w * 4;
    const u16* rp[8];
    f32x4 acc[2][4];

    if (blockIdx.z == 8) {
#pragma unroll
        for (int i = 0; i < 8; ++i)
            rp[i] = h1 + (size_t)(m0 + w * 8 + i) * DFFN + ks * 1024;
        gemm32<2>(rp, fc2p + (size_t)f0 * 32768, 64, ks * 32, acc, As);
        u16* dst = pf + (size_t)ks * TTOK * DMOD;
#pragma unroll
        for (int mi = 0; mi < 2; ++mi)
#pragma unroll
            for (int nj = 0; nj < 4; ++nj) {
                int col = (f0 + nj) * 16 + cb;
#pragma unroll
                for (int r = 0; r < 4; ++r) {
                    int row = m0 + mi * 16 + rq + r;
                    dst[(size_t)row * DMOD + col] = to_bf16(acc[mi][nj][r]);
                }
            }
    } else {
        const int e = blockIdx.z, ce = cnt[e];
        if (m0 >= ce) return;
        const int* sl = slots + e * TTOK;
#pragma unroll
        for (int i = 0; i < 8; ++i) {
            int p = m0 + w * 8 + i; if (p > ce - 1) p = ce - 1;
            rp[i] = hbuf + (size_t)sl[p] * HEXP + ks * 512;
        }
        gemm32<1>(rp, w2p + (size_t)e * 524288 + (size_t)f0 * 16384, 32, ks * 16, acc, As);
        u16* dst = pm + (size_t)ks * 2 * TTOK * DMOD;
#pragma unroll
        for (int mi = 0; mi < 2; ++mi)
#pragma unroll
            for (int r = 0; r < 4; ++r) {
                int p = m0 + mi * 16 + rq + r;
                if (p < ce) {
                    int slot = sl[p];
#pragma unroll
                    for (int nj = 0; nj < 4; ++nj) {
                        int col = (f0 + nj) * 16 + cb;
                        dst[(size_t)slot * DMOD + col] = to_bf16(acc[mi][nj][r]);
                    }
                }
            }
    }
}

// ---------------- combine: out = hidden + ffn2(+bias) + alpha*(gated moe(+bias)) ----------------
__global__ __launch_bounds__(256) void combine_kernel(
    const float* __restrict__ hidden, const u16* __restrict__ pf, const u16* __restrict__ pm,
    const float* __restrict__ fc2_b, const float* __restrict__ b2,
    const float* __restrict__ gslot, const int* __restrict__ eslot,
    const float* __restrict__ alpha, float* __restrict__ out)
{
    int i = blockIdx.x * 256 + threadIdx.x;     // float4 index over T*D/4
    int t = i >> 7, d = (i & 127) * 4;
    float a = alpha[0];
    float4 h = ((const float4*)hidden)[i];
    float4 bias = *(const float4*)(fc2_b + d);

    size_t fo = (size_t)t * DMOD + d;
    float4 f0 = ld_bf4(pf + fo), f1 = ld_bf4(pf + (size_t)TTOK * DMOD + fo);

    int s0 = 2 * t, s1 = 2 * t + 1;
    float g0 = gslot[s0], g1 = gslot[s1];
    int e0 = eslot[s0], e1 = eslot[s1];
    size_t mo0 = (size_t)s0 * DMOD + d, mo1 = (size_t)s1 * DMOD + d;
    const u16* pm1 = pm + (size_t)2 * TTOK * DMOD;
    float4 ma = ld_bf4(pm + mo0), mb = ld_bf4(pm1 + mo0);
    float4 mc = ld_bf4(pm + mo1), md = ld_bf4(pm1 + mo1);
    float4 ba = *(const float4*)(b2 + e0 * DMOD + d);
    float4 bb = *(const float4*)(b2 + e1 * DMOD + d);

    float4 o;
    o.x = h.x + f0.x + f1.x + bias.x + a * (g0 * (ma.x + mb.x + ba.x) + g1 * (mc.x + md.x + bb.x));
    o.y = h.y + f0.y + f1.y + bias.y + a * (g0 * (ma.y + mb.y + ba.y) + g1 * (mc.y + md.y + bb.y));
    o.z = h.z + f0.z + f1.z + bias.z + a * (g0 * (ma.z + mb.z + ba.z) + g1 * (mc.z + md.z + bb.z));
    o.w = h.w + f0.w + f1.w + bias.w + a * (g0 * (ma.w + mb.w + ba.w) + g1 * (mc.w + md.w + bb.w));
    ((float4*)out)[i] = o;
}

extern "C" void kernel_launch(void* const* d_in, const int* in_sizes, int n_in,
                              void* d_out, int out_size, void* d_ws, size_t ws_size,
                              hipStream_t stream)
{
    const float* hidden   = (const float*)d_in[0];
    const float* raw      = (const float*)d_in[1];
    const float* ln_g     = (const float*)d_in[2];
    const float* ln_b     = (const float*)d_in[3];
    const float* pre_g    = (const float*)d_in[4];
    const float* pre_b    = (const float*)d_in[5];
    const float* feat_w   = (const float*)d_in[6];
    const float* feat_b   = (const float*)d_in[7];
    const float* film_w   = (const float*)d_in[8];
    const float* film_b   = (const float*)d_in[9];
    const float* router_w = (const float*)d_in[10];
    const float* router_b = (const float*)d_in[11];
    const float* w1       = (const float*)d_in[12];
    const float* b1       = (const float*)d_in[13];
    const float* w2       = (const float*)d_in[14];
    const float* b2       = (const float*)d_in[15];
    const float* fc1_w    = (const float*)d_in[16];
    const float* fc1_b    = (const float*)d_in[17];
    const float* fc2_w    = (const float*)d_in[18];
    const float* fc2_b    = (const float*)d_in[19];
    const float* alpha    = (const float*)d_in[20];
    float* out = (float*)d_out;

    char* w = (char*)d_ws;
    auto alloc = [&](size_t b) { char* p = w; w += (b + 255) & ~(size_t)255; return p; };
    u16*  fc1p = (u16*)alloc((size_t)DFFN * DMOD * 2);
    u16*  fc2p = (u16*)alloc((size_t)DMOD * DFFN * 2);
    u16*  w1p  = (u16*)alloc((size_t)NEXP * HEXP * DMOD * 2);
    u16*  w2p  = (u16*)alloc((size_t)NEXP * DMOD * HEXP * 2);
    u16*  xs   = (u16*)alloc((size_t)TTOK * DMOD * 2);
    u16*  xin  = (u16*)alloc((size_t)TTOK * DMOD * 2);
    u16*  h1   = (u16*)alloc((size_t)TTOK * DFFN * 2);
    u16*  hb   = (u16*)alloc((size_t)2 * TTOK * HEXP * 2);
    u16*  pf   = (u16*)alloc((size_t)2 * TTOK * DMOD * 2);
    u16*  pm   = (u16*)alloc((size_t)2 * 2 * TTOK * DMOD * 2);
    int*   cnt   = (int*)alloc(NEXP * 4);
    int*   slots = (int*)alloc((size_t)NEXP * TTOK * 4);
    float* gslot = (float*)alloc((size_t)2 * TTOK * 4);
    int*   eslot = (int*)alloc((size_t)2 * TTOK * 4);
    float* logits = (float*)alloc((size_t)TTOK * 8 * 4);
    float* xbuf  = (float*)pm;      // fp32 [T,D]=8MB, consumed by film before stage2 writes pm
    float* featbuf = (float*)h1;    // 1MB, consumed by film before stage1 writes h1

    hipMemsetAsync(cnt, 0, NEXP * 4, stream);
    pack_weights<<<5120, 256, 0, stream>>>(fc1_w, fc2_w, w1, w2, fc1p, fc2p, w1p, w2p);
    ln_kernel<<<1024, 256, 0, stream>>>(hidden, raw, ln_g, ln_b, pre_g, pre_b,
        feat_w, feat_b, router_w, router_b, xs, xbuf, featbuf, logits);
    bucket_kernel<<<16, 256, 0, stream>>>(logits, cnt, slots, gslot, eslot);
    film_kernel<<<512, 256, 0, stream>>>(xbuf, featbuf, film_w, film_b, xin);
    stage1_kernel<<<dim3(128, 8, 9), 256, 0, stream>>>(xs, fc1p, fc1_b, h1,
        xin, w1p, b1, cnt, slots, hb);
    stage2_kernel<<<dim3(128, 4, 9), 256, 0, stream>>>(h1, fc2p, hb, w2p, cnt, slots, pf, pm);
    combine_kernel<<<2048, 256, 0, stream>>>(hidden, pf, pm, fc2_b, b2, gslot, eslot, alpha, out);
}